// Round 2
// baseline (474.391 us; speedup 1.0000x reference)
//
#include <hip/hip_runtime.h>
#include <hip/hip_bf16.h>

// Problem constants
#define BB 2
#define CC 2
#define NN 1024
#define F0V 64
#define HH 8
#define FFV 64
// derived
#define BCHN (BB*CC*HH)          // 32
#define HPN  (BB*CC*HH*NN*FFV)   // 4194304 floats per big buffer
#define SVN  (BB*CC*HH*NN)       // 32768

__device__ __forceinline__ float wsum16(float v){
  #pragma unroll
  for (int off = 1; off < 16; off <<= 1) v += __shfl_xor(v, off);
  return v;
}
__device__ __forceinline__ float wsum64(float v){
  #pragma unroll
  for (int off = 1; off < 64; off <<= 1) v += __shfl_xor(v, off);
  return v;
}
__device__ __forceinline__ float wmax16(float v){
  #pragma unroll
  for (int off = 1; off < 16; off <<= 1) v = fmaxf(v, __shfl_xor(v, off));
  return v;
}
__device__ __forceinline__ void fma4(float4& a, float p, const float4 h){
  a.x = fmaf(p, h.x, a.x); a.y = fmaf(p, h.y, a.y);
  a.z = fmaf(p, h.z, a.z); a.w = fmaf(p, h.w, a.w);
}

// ---------------- Layer-1 projection: Hp1 = x @ w1, s1/d1 = tanh(Hp1)·a ----------------
// grid (N/4, 32), block 256 (4 waves, 1 row per wave, lane = output feature)
__global__ __launch_bounds__(256) void proj1_kernel(
    const float* __restrict__ x,  const float* __restrict__ w1,
    const float* __restrict__ asrc, const float* __restrict__ adst,
    float* __restrict__ Hp, float* __restrict__ s_out, float* __restrict__ d_out)
{
  __shared__ float wt[F0V*FFV];
  __shared__ float asr[FFV], ads[FFV];
  __shared__ float xs[4][F0V];
  const int bch = blockIdx.y;
  const int h = bch % HH; const int bc = bch / HH; const int c = bc % CC;
  const int t = threadIdx.x;
  const float* wsrc = w1 + (size_t)(c*HH + h) * (F0V*FFV);
  {
    const float4* s4 = (const float4*)wsrc;
    float4* d4 = (float4*)wt;
    #pragma unroll
    for (int j = 0; j < 4; ++j) d4[t + j*256] = s4[t + j*256];
  }
  if (t < FFV) {
    asr[t] = asrc[(c*HH + h)*FFV + t];
    ads[t] = adst[(c*HH + h)*FFV + t];
  }
  const int w = t >> 6, lane = t & 63;
  const int n = blockIdx.x*4 + w;
  xs[w][lane] = x[((size_t)bc*NN + n)*F0V + lane];
  __syncthreads();
  float hp = 0.f;
  #pragma unroll
  for (int i = 0; i < F0V; ++i) hp = fmaf(xs[w][i], wt[i*FFV + lane], hp);
  Hp[((size_t)bch*NN + n)*FFV + lane] = hp;
  const float tt = tanhf(hp);
  const float sv = wsum64(tt * asr[lane]);
  const float dv = wsum64(tt * ads[lane]);
  if (lane == 0) { s_out[bch*NN + n] = sv; d_out[bch*NN + n] = dv; }
}

// ---------------- Layer-2 projection: Hp2 = x1 @ w2 (K=512) ----------------
// grid (N/8, 32), block 512 (8 waves, 1 row per wave)
__global__ __launch_bounds__(512) void proj2_kernel(
    const float* __restrict__ x1, const float* __restrict__ w2,
    const float* __restrict__ asrc, const float* __restrict__ adst,
    float* __restrict__ Hp, float* __restrict__ s_out, float* __restrict__ d_out)
{
  __shared__ float wt[64*FFV];
  __shared__ float asr[FFV], ads[FFV];
  __shared__ float xs[8][64];
  const int bch = blockIdx.y;
  const int h = bch % HH; const int bc = bch / HH; const int c = bc % CC;
  const int t = threadIdx.x;
  if (t < FFV) {
    asr[t] = asrc[(c*HH + h)*FFV + t];
    ads[t] = adst[(c*HH + h)*FFV + t];
  }
  const int w = t >> 6, lane = t & 63;
  const int n = blockIdx.x*8 + w;
  const float* wsrc = w2 + (size_t)(c*HH + h) * (512*FFV);
  const float* xrow = x1 + ((size_t)bc*NN + n)*512;
  float hp = 0.f;
  for (int kc = 0; kc < 8; ++kc) {
    __syncthreads();
    {
      const float4* s4 = (const float4*)(wsrc + (size_t)kc*64*FFV);
      float4* d4 = (float4*)wt;
      #pragma unroll
      for (int j = 0; j < 2; ++j) d4[t + j*512] = s4[t + j*512];
    }
    xs[w][lane] = xrow[kc*64 + lane];
    __syncthreads();
    #pragma unroll
    for (int i = 0; i < 64; ++i) hp = fmaf(xs[w][i], wt[i*FFV + lane], hp);
  }
  Hp[((size_t)bch*NN + n)*FFV + lane] = hp;
  const float tt = tanhf(hp);
  const float sv = wsum64(tt * asr[lane]);
  const float dv = wsum64(tt * ads[lane]);
  if (lane == 0) { s_out[bch*NN + n] = sv; d_out[bch*NN + n] = dv; }
}

// ---------------- Attention: out[n,:] = softmax_m(LRelu(s[n]+d[m]) masked) @ Hp ----------------
// grid (N/16, 32), block 256. Row r = t/16, lane-in-group g = t%16 (4 features each).
// LAYER==1: write x1[b,c,n,h*64+f] = elu(out); LAYER==2: write out2[b,c,h,n,f].
template<int LAYER>
__global__ __launch_bounds__(256) void attn_kernel(
    const float* __restrict__ Hp, const float* __restrict__ s_arr, const float* __restrict__ d_arr,
    const int* __restrict__ adj, float* __restrict__ outp)
{
  __shared__ float dvec[NN];        // 4 KB
  __shared__ float hpc[64*FFV];     // 16 KB: 64 m-rows x 64 features
  __shared__ float pch[16*64];      // 4 KB: 16 rows x 64 m
  const int bch = blockIdx.y;
  const int h = bch % HH; const int bc = bch / HH; const int b = bc / CC;
  const int t = threadIdx.x;
  ((float4*)dvec)[t] = ((const float4*)(d_arr + (size_t)bch*NN))[t];
  const int r = t >> 4, g = t & 15;
  const int row = blockIdx.x*16 + r;
  const float s = s_arr[(size_t)bch*NN + row];
  const int* __restrict__ adjrow = adj + ((size_t)b*NN + row)*NN;
  __syncthreads();

  // pass 1: row max over allowed entries (diagonal always allowed: self-loop)
  float mx = -1e30f;
  #pragma unroll 4
  for (int k = 0; k < 64; ++k) {
    const int m = g + k*16;
    float e = s + dvec[m];
    e = e >= 0.f ? e : 0.2f*e;
    const bool allowed = (adjrow[m] != 0) || (m == row);
    if (allowed) mx = fmaxf(mx, e);
  }
  mx = wmax16(mx);

  float4 acc = {0.f, 0.f, 0.f, 0.f};
  float dsum = 0.f;
  const float4* hp4s = (const float4*)(Hp + (size_t)bch*NN*FFV);

  for (int mc = 0; mc < 16; ++mc) {
    __syncthreads();  // previous chunk's readers done
    // stage Hp chunk: rows mc*64 .. mc*64+63
    {
      const float4* src = hp4s + (size_t)mc*64*16;
      float4* dst = (float4*)hpc;
      #pragma unroll
      for (int j = 0; j < 4; ++j) dst[t + j*256] = src[t + j*256];
    }
    // compute p for this chunk
    #pragma unroll
    for (int k = 0; k < 4; ++k) {
      const int ml = g + k*16;
      const int m = mc*64 + ml;
      float e = s + dvec[m];
      e = e >= 0.f ? e : 0.2f*e;
      const bool allowed = (adjrow[m] != 0) || (m == row);
      const float pv = allowed ? __expf(e - mx) : 0.f;
      pch[r*64 + ml] = pv;
      dsum += pv;
    }
    __syncthreads();
    // accumulate: acc[f] += p[m] * Hp[m,f], f = 4g..4g+3
    const float4* hp4 = (const float4*)hpc;
    const float4* p4 = ((const float4*)pch) + r*16;
    #pragma unroll
    for (int i4 = 0; i4 < 16; ++i4) {
      const float4 pq = p4[i4];
      float4 hv;
      hv = hp4[(i4*4+0)*16 + g]; fma4(acc, pq.x, hv);
      hv = hp4[(i4*4+1)*16 + g]; fma4(acc, pq.y, hv);
      hv = hp4[(i4*4+2)*16 + g]; fma4(acc, pq.z, hv);
      hv = hp4[(i4*4+3)*16 + g]; fma4(acc, pq.w, hv);
    }
  }
  dsum = wsum16(dsum);
  const float inv = 1.f / dsum;
  acc.x *= inv; acc.y *= inv; acc.z *= inv; acc.w *= inv;

  if (LAYER == 1) {
    float4 o;
    o.x = acc.x > 0.f ? acc.x : expm1f(acc.x);
    o.y = acc.y > 0.f ? acc.y : expm1f(acc.y);
    o.z = acc.z > 0.f ? acc.z : expm1f(acc.z);
    o.w = acc.w > 0.f ? acc.w : expm1f(acc.w);
    ((float4*)(outp + ((size_t)bc*NN + row)*(HH*FFV) + h*FFV))[g] = o;
  } else {
    ((float4*)(outp + ((size_t)bch*NN + row)*FFV))[g] = acc;
  }
}

// ---------------- Mean over heads -> fp32 out ----------------
__global__ __launch_bounds__(256) void reduce_heads(
    const float* __restrict__ out2, float* __restrict__ out)
{
  const int o = blockIdx.x*256 + threadIdx.x;    // [bc, n, f] flat, 262144 total
  const int f = o & 63;
  const int n = (o >> 6) & (NN - 1);
  const int bc = o >> 16;
  float acc = 0.f;
  #pragma unroll
  for (int h = 0; h < HH; ++h)
    acc += out2[(((size_t)bc*HH + h)*NN + n)*FFV + f];
  out[o] = acc * 0.125f;
}

extern "C" void kernel_launch(void* const* d_in, const int* in_sizes, int n_in,
                              void* d_out, int out_size, void* d_ws, size_t ws_size,
                              hipStream_t stream)
{
  const float* x   = (const float*)d_in[0];
  const int*   adj = (const int*)d_in[1];
  const float* w1  = (const float*)d_in[2];
  const float* as1 = (const float*)d_in[3];
  const float* ad1 = (const float*)d_in[4];
  const float* w2  = (const float*)d_in[5];
  const float* as2 = (const float*)d_in[6];
  const float* ad2 = (const float*)d_in[7];

  // Workspace layout with lifetime-based reuse (peak 32.25 MB):
  //   BIG_A: Hp1 (dead after attn<1>) then Hp2
  //   BIG_B: x1  (dead after proj2)   then out2
  float* ws   = (float*)d_ws;
  float* BIG_A = ws;                    // 4194304 floats
  float* BIG_B = BIG_A + HPN;           // 4194304 floats
  float* s_v  = BIG_B + HPN;            // 32768
  float* d_v  = s_v + SVN;              // 32768

  float* Hp1 = BIG_A, *Hp2 = BIG_A;
  float* x1  = BIG_B, *out2 = BIG_B;

  proj1_kernel<<<dim3(NN/4, BCHN), 256, 0, stream>>>(x, w1, as1, ad1, Hp1, s_v, d_v);
  attn_kernel<1><<<dim3(NN/16, BCHN), 256, 0, stream>>>(Hp1, s_v, d_v, adj, x1);
  proj2_kernel<<<dim3(NN/8, BCHN), 512, 0, stream>>>(x1, w2, as2, ad2, Hp2, s_v, d_v);
  attn_kernel<2><<<dim3(NN/16, BCHN), 256, 0, stream>>>(Hp2, s_v, d_v, adj, out2);
  reduce_heads<<<dim3((unsigned)(out_size/256)), 256, 0, stream>>>(out2, (float*)d_out);
}

// Round 3
// 297.257 us; speedup vs baseline: 1.5959x; 1.5959x over previous
//
#include <hip/hip_runtime.h>
#include <hip/hip_bf16.h>

#define BB 2
#define CC 2
#define NN 1024
#define F0V 64
#define HH 8
#define FFV 64
#define BCHN (BB*CC*HH)          // 32
#define SVN  (BB*CC*HH*NN)       // 32768

typedef _Float16 f16x8 __attribute__((ext_vector_type(8)));
typedef float f32x4 __attribute__((ext_vector_type(4)));

__device__ __forceinline__ float wsum64(float v){
  #pragma unroll
  for (int off = 1; off < 64; off <<= 1) v += __shfl_xor(v, off);
  return v;
}
__device__ __forceinline__ float wmax64(float v){
  #pragma unroll
  for (int off = 1; off < 64; off <<= 1) v = fmaxf(v, __shfl_xor(v, off));
  return v;
}

// ---------------- Packed adjacency bitmask: bmg[b][n][16] u64, bit m = allowed ----------------
__global__ __launch_bounds__(256) void build_mask(const int* __restrict__ adj,
                                                  unsigned long long* __restrict__ bmg)
{
  const int wg = blockIdx.x*4 + (threadIdx.x >> 6);   // 64 blocks x 4 waves = 256 waves
  const int lane = threadIdx.x & 63;
  for (int idx = wg; idx < BB*NN*16; idx += 256) {
    const int b = idx >> 14;
    const int n = (idx >> 4) & (NN - 1);
    const int word = idx & 15;
    const int m = word*64 + lane;
    const int pred = (adj[((size_t)b*NN + n)*NN + m] != 0) || (m == n);
    unsigned long long bits = __ballot(pred);
    if (lane == 0) bmg[idx] = bits;
  }
}

// ---------------- Layer-1 projection: Hp1 = x @ w1 (fp16 out), s1/d1 = tanh(Hp1)·a ----------------
__global__ __launch_bounds__(256) void proj1_kernel(
    const float* __restrict__ x,  const float* __restrict__ w1,
    const float* __restrict__ asrc, const float* __restrict__ adst,
    _Float16* __restrict__ Hp, float* __restrict__ s_out, float* __restrict__ d_out)
{
  __shared__ float wt[F0V*FFV];
  __shared__ float asr[FFV], ads[FFV];
  __shared__ float xs[4][F0V];
  const int bch = blockIdx.y;
  const int h = bch % HH; const int bc = bch / HH; const int c = bc % CC;
  const int t = threadIdx.x;
  const float* wsrc = w1 + (size_t)(c*HH + h) * (F0V*FFV);
  {
    const float4* s4 = (const float4*)wsrc;
    float4* d4 = (float4*)wt;
    #pragma unroll
    for (int j = 0; j < 4; ++j) d4[t + j*256] = s4[t + j*256];
  }
  if (t < FFV) {
    asr[t] = asrc[(c*HH + h)*FFV + t];
    ads[t] = adst[(c*HH + h)*FFV + t];
  }
  const int w = t >> 6, lane = t & 63;
  const int n = blockIdx.x*4 + w;
  xs[w][lane] = x[((size_t)bc*NN + n)*F0V + lane];
  __syncthreads();
  float hp = 0.f;
  #pragma unroll
  for (int i = 0; i < F0V; ++i) hp = fmaf(xs[w][i], wt[i*FFV + lane], hp);
  Hp[((size_t)bch*NN + n)*FFV + lane] = (_Float16)hp;
  const float tt = tanhf(hp);
  const float sv = wsum64(tt * asr[lane]);
  const float dv = wsum64(tt * ads[lane]);
  if (lane == 0) { s_out[bch*NN + n] = sv; d_out[bch*NN + n] = dv; }
}

// ---------------- Layer-2 projection: Hp2 = x1 @ w2 (K=512), x1 fp16 in, fp16 out ----------------
__global__ __launch_bounds__(512) void proj2_kernel(
    const _Float16* __restrict__ x1, const float* __restrict__ w2,
    const float* __restrict__ asrc, const float* __restrict__ adst,
    _Float16* __restrict__ Hp, float* __restrict__ s_out, float* __restrict__ d_out)
{
  __shared__ float wt[64*FFV];
  __shared__ float asr[FFV], ads[FFV];
  __shared__ float xs[8][64];
  const int bch = blockIdx.y;
  const int h = bch % HH; const int bc = bch / HH; const int c = bc % CC;
  const int t = threadIdx.x;
  if (t < FFV) {
    asr[t] = asrc[(c*HH + h)*FFV + t];
    ads[t] = adst[(c*HH + h)*FFV + t];
  }
  const int w = t >> 6, lane = t & 63;
  const int n = blockIdx.x*8 + w;
  const float* wsrc = w2 + (size_t)(c*HH + h) * (512*FFV);
  const _Float16* xrow = x1 + ((size_t)bc*NN + n)*512;
  float hp = 0.f;
  for (int kc = 0; kc < 8; ++kc) {
    __syncthreads();
    {
      const float4* s4 = (const float4*)(wsrc + (size_t)kc*64*FFV);
      float4* d4 = (float4*)wt;
      #pragma unroll
      for (int j = 0; j < 2; ++j) d4[t + j*512] = s4[t + j*512];
    }
    xs[w][lane] = (float)xrow[kc*64 + lane];
    __syncthreads();
    #pragma unroll
    for (int i = 0; i < 64; ++i) hp = fmaf(xs[w][i], wt[i*FFV + lane], hp);
  }
  Hp[((size_t)bch*NN + n)*FFV + lane] = (_Float16)hp;
  const float tt = tanhf(hp);
  const float sv = wsum64(tt * asr[lane]);
  const float dv = wsum64(tt * ads[lane]);
  if (lane == 0) { s_out[bch*NN + n] = sv; d_out[bch*NN + n] = dv; }
}

// ---------------- Transpose Hp [bch][N][64] f16 -> HpT [bch][64][N] f16 ----------------
__global__ __launch_bounds__(256) void transpose64(const _Float16* __restrict__ src,
                                                   _Float16* __restrict__ dst)
{
  __shared__ __align__(16) _Float16 tile[64*66];   // [f][66] f-major
  const int bch = blockIdx.y;
  const int n0 = blockIdx.x*64;
  const int t = threadIdx.x;
  #pragma unroll
  for (int i = 0; i < 2; ++i) {
    const int u = t + i*256;
    const int n = u >> 3, fs = u & 7;
    const f16x8 v = *(const f16x8*)(src + ((size_t)bch*NN + n0 + n)*64 + fs*8);
    #pragma unroll
    for (int j = 0; j < 8; ++j) tile[(fs*8 + j)*66 + n] = v[j];
  }
  __syncthreads();
  #pragma unroll
  for (int i = 0; i < 2; ++i) {
    const int u = t + i*256;
    const int f = u >> 3, ns = u & 7;
    const int hb = f*66 + ns*8;       // byte offset hb*2 is 4-aligned (66*2=132)
    uint4 o;
    o.x = *(const unsigned int*)&tile[hb + 0];
    o.y = *(const unsigned int*)&tile[hb + 2];
    o.z = *(const unsigned int*)&tile[hb + 4];
    o.w = *(const unsigned int*)&tile[hb + 6];
    *(uint4*)(dst + ((size_t)bch*64 + f)*NN + n0 + ns*8) = o;
  }
}

// ---------------- Fused attention: P on-the-fly -> MFMA PV -> normalize ----------------
// grid (N/32, 32 bch), 256 thr. Wave w owns features w*16..+15; 2 M-tiles of 16 rows.
// P-compute: thread t -> row pr=t>>3, k-slot pk=t&7 (16 k each per 128-chunk).
template<int LAYER>
__global__ __launch_bounds__(256) void attn_mfma(
    const _Float16* __restrict__ HpT, const float* __restrict__ s_arr,
    const float* __restrict__ d_arr, const unsigned long long* __restrict__ bmg,
    _Float16* __restrict__ outp)
{
  __shared__ __align__(16) _Float16 Bl[64*136];   // HpT chunk [f][136 (128 k + pad)]
  __shared__ __align__(16) _Float16 Al[32*136];   // P chunk  [r][136]
  __shared__ __align__(16) float d_lds[NN];
  __shared__ float dsum_lds[32];
  __shared__ float red4[4];
  const int bch = blockIdx.y;
  const int b = bch / (CC*HH);
  const int row0 = blockIdx.x*32;
  const int t = threadIdx.x;
  const int w = t >> 6, lane = t & 63;

  // stage d, compute maxd
  float4 dv4 = ((const float4*)(d_arr + (size_t)bch*NN))[t];
  ((float4*)d_lds)[t] = dv4;
  float mx = fmaxf(fmaxf(dv4.x, dv4.y), fmaxf(dv4.z, dv4.w));
  mx = wmax64(mx);
  if (lane == 0) red4[w] = mx;
  __syncthreads();
  const float maxd = fmaxf(fmaxf(red4[0], red4[1]), fmaxf(red4[2], red4[3]));

  const int pr = t >> 3, pk = t & 7;
  const int rowg = row0 + pr;
  const float s_raw = s_arr[(size_t)bch*NN + rowg];
  const float so = s_raw + maxd;
  const float offs = fmaxf(so, 0.2f*so);          // lrelu(s+maxd): upper bound of lrelu(s+d)
  const unsigned long long* bmrow = bmg + ((size_t)b*NN + rowg)*16;
  float dsum = 0.f;
  f32x4 acc0 = {0.f,0.f,0.f,0.f}, acc1 = {0.f,0.f,0.f,0.f};
  const _Float16* Bg = HpT + (size_t)bch*64*NN;
  const int colr = lane & 15, quad = lane >> 4;

  for (int kc = 0; kc < NN; kc += 128) {
    // stage B chunk (64 f x 128 k), coalesced 16B
    #pragma unroll
    for (int j = 0; j < 4; ++j) {
      const int u = t + j*256;
      const int f = u >> 4, seg = u & 15;
      *(uint4*)&Bl[f*136 + seg*8] = *(const uint4*)(Bg + (size_t)f*NN + kc + seg*8);
    }
    // compute P (fp32 -> fp16), accumulate fp32 dsum
    const int kg0 = kc + pk*16;
    const unsigned mb = (unsigned)((bmrow[kg0 >> 6] >> (kg0 & 63)) & 0xFFFFull);
    const float4* dp = (const float4*)&d_lds[kg0];
    float4 q0 = dp[0], q1 = dp[1], q2 = dp[2], q3 = dp[3];
    const float dd[16] = {q0.x,q0.y,q0.z,q0.w, q1.x,q1.y,q1.z,q1.w,
                          q2.x,q2.y,q2.z,q2.w, q3.x,q3.y,q3.z,q3.w};
    f16x8 p0, p1;
    #pragma unroll
    for (int i = 0; i < 16; ++i) {
      const float e0 = s_raw + dd[i];
      const float e = fmaxf(e0, 0.2f*e0);
      const float p = ((mb >> i) & 1u) ? __expf(e - offs) : 0.f;
      dsum += p;
      if (i < 8) p0[i] = (_Float16)p; else p1[i-8] = (_Float16)p;
    }
    *(f16x8*)&Al[pr*136 + pk*16]     = p0;
    *(f16x8*)&Al[pr*136 + pk*16 + 8] = p1;
    __syncthreads();
    // MFMA: 4 K-steps of 32
    #pragma unroll
    for (int ks = 0; ks < 4; ++ks) {
      const int kk = ks*32 + quad*8;
      const f16x8 bf = *(const f16x8*)&Bl[(w*16 + colr)*136 + kk];
      const f16x8 a0 = *(const f16x8*)&Al[colr*136 + kk];
      const f16x8 a1 = *(const f16x8*)&Al[(16 + colr)*136 + kk];
      acc0 = __builtin_amdgcn_mfma_f32_16x16x32_f16(a0, bf, acc0, 0, 0, 0);
      acc1 = __builtin_amdgcn_mfma_f32_16x16x32_f16(a1, bf, acc1, 0, 0, 0);
    }
    __syncthreads();
  }
  // row denominators
  dsum += __shfl_xor(dsum, 1);
  dsum += __shfl_xor(dsum, 2);
  dsum += __shfl_xor(dsum, 4);
  if (pk == 0) dsum_lds[pr] = dsum;
  __syncthreads();

  // epilogue: C/D layout col=lane&15, row=quad*4+i
  const int bc = bch / HH, h = bch % HH;
  #pragma unroll
  for (int mt = 0; mt < 2; ++mt) {
    const f32x4 a = mt ? acc1 : acc0;
    #pragma unroll
    for (int i = 0; i < 4; ++i) {
      const int rr = mt*16 + quad*4 + i;
      const float v = a[i] / dsum_lds[rr];
      if (LAYER == 1) {
        const float o = v > 0.f ? v : expm1f(v);
        outp[((size_t)bc*NN + row0 + rr)*512 + h*64 + w*16 + colr] = (_Float16)o;
      } else {
        outp[((size_t)bch*NN + row0 + rr)*64 + w*16 + colr] = (_Float16)v;
      }
    }
  }
}

// ---------------- Mean over heads (f16 in) -> fp32 out ----------------
__global__ __launch_bounds__(256) void reduce_heads(
    const _Float16* __restrict__ out2, float* __restrict__ out)
{
  const int o = blockIdx.x*256 + threadIdx.x;    // [bc, n, f] flat, 262144
  const int f = o & 63;
  const int n = (o >> 6) & (NN - 1);
  const int bc = o >> 16;
  float acc = 0.f;
  #pragma unroll
  for (int h = 0; h < HH; ++h)
    acc += (float)out2[(((size_t)bc*HH + h)*NN + n)*FFV + f];
  out[o] = acc * 0.125f;
}

extern "C" void kernel_launch(void* const* d_in, const int* in_sizes, int n_in,
                              void* d_out, int out_size, void* d_ws, size_t ws_size,
                              hipStream_t stream)
{
  const float* x   = (const float*)d_in[0];
  const int*   adj = (const int*)d_in[1];
  const float* w1  = (const float*)d_in[2];
  const float* as1 = (const float*)d_in[3];
  const float* ad1 = (const float*)d_in[4];
  const float* w2  = (const float*)d_in[5];
  const float* as2 = (const float*)d_in[6];
  const float* ad2 = (const float*)d_in[7];

  // Workspace (12.5 MB total):
  char* w8 = (char*)d_ws;
  _Float16* Hph = (_Float16*)(w8);                         // 4 MB: Hp f16 [bch][N][64]
  _Float16* HpT = (_Float16*)(w8 + (4u<<20));              // 4 MB: HpT f16 [bch][64][N]
  _Float16* XB  = (_Float16*)(w8 + (8u<<20));              // 4 MB: x1 [bc][N][512] then out2 [bch][N][64]
  float* s_v = (float*)(w8 + (12u<<20));                   // 128 KB
  float* d_v = (float*)(w8 + (12u<<20) + SVN*4);           // 128 KB
  unsigned long long* bmg = (unsigned long long*)(w8 + (12u<<20) + SVN*8);  // 256 KB

  build_mask<<<64, 256, 0, stream>>>(adj, bmg);
  proj1_kernel<<<dim3(NN/4, BCHN), 256, 0, stream>>>(x, w1, as1, ad1, Hph, s_v, d_v);
  transpose64<<<dim3(NN/64, BCHN), 256, 0, stream>>>(Hph, HpT);
  attn_mfma<1><<<dim3(NN/32, BCHN), 256, 0, stream>>>(HpT, s_v, d_v, bmg, XB);
  proj2_kernel<<<dim3(NN/8, BCHN), 512, 0, stream>>>(XB, w2, as2, ad2, Hph, s_v, d_v);
  transpose64<<<dim3(NN/64, BCHN), 256, 0, stream>>>(Hph, HpT);
  attn_mfma<2><<<dim3(NN/32, BCHN), 256, 0, stream>>>(HpT, s_v, d_v, bmg, XB);
  reduce_heads<<<dim3((unsigned)(out_size/256)), 256, 0, stream>>>(XB, (float*)d_out);
}

// Round 4
// 174.354 us; speedup vs baseline: 2.7208x; 1.7049x over previous
//
#include <hip/hip_runtime.h>
#include <hip/hip_bf16.h>

#define BB 2
#define CC 2
#define NN 1024
#define F0V 64
#define HH 8
#define FFV 64
#define BCHN (BB*CC*HH)          // 32
#define SVN  (BB*CC*HH*NN)       // 32768

typedef _Float16 f16x8 __attribute__((ext_vector_type(8)));
typedef _Float16 f16x4 __attribute__((ext_vector_type(4)));
typedef float f32x4 __attribute__((ext_vector_type(4)));

// ---------------- Packed adjacency bitmask: bmg[b][n][16] u64, bit m = allowed ----------------
__global__ __launch_bounds__(256) void build_mask(const int* __restrict__ adj,
                                                  unsigned long long* __restrict__ bmg)
{
  const int wg = blockIdx.x*4 + (threadIdx.x >> 6);   // 256 blocks x 4 waves = 1024 waves
  const int lane = threadIdx.x & 63;
  for (int idx = wg; idx < BB*NN*16; idx += 1024) {
    const int b = idx >> 14;
    const int n = (idx >> 4) & (NN - 1);
    const int word = idx & 15;
    const int m = word*64 + lane;
    const int pred = (adj[((size_t)b*NN + n)*NN + m] != 0) || (m == n);
    unsigned long long bits = __ballot(pred);
    if (lane == 0) bmg[idx] = bits;
  }
}

// ---------------- Convert x fp32 -> f16 ----------------
__global__ __launch_bounds__(256) void convert_x(const float* __restrict__ x,
                                                 _Float16* __restrict__ xh)
{
  const int i = blockIdx.x*256 + threadIdx.x;     // 65536 threads x 4 elems
  const float4 v = ((const float4*)x)[i];
  f16x4 o; o[0]=(_Float16)v.x; o[1]=(_Float16)v.y; o[2]=(_Float16)v.z; o[3]=(_Float16)v.w;
  ((f16x4*)xh)[i] = o;
}

// ---------------- Transpose weights: w [ch][K][64] fp32 -> wT [ch][64][K] f16 ----------------
__global__ __launch_bounds__(256) void transpose_w(const float* __restrict__ w,
                                                   _Float16* __restrict__ wT, int K)
{
  __shared__ __align__(16) _Float16 tile[64*72];
  const int ch = blockIdx.y, k0 = blockIdx.x*64;
  const int t = threadIdx.x;
  const float* src = w + ((size_t)ch*K + k0)*64;
  #pragma unroll
  for (int j = 0; j < 4; ++j) {
    const int u = t + j*256;             // 1024 float4 units: 64 k x 16 segs
    const int k = u >> 4, seg = u & 15;
    const float4 v = ((const float4*)src)[(size_t)k*16 + seg];
    tile[(seg*4+0)*72 + k] = (_Float16)v.x;
    tile[(seg*4+1)*72 + k] = (_Float16)v.y;
    tile[(seg*4+2)*72 + k] = (_Float16)v.z;
    tile[(seg*4+3)*72 + k] = (_Float16)v.w;
  }
  __syncthreads();
  _Float16* dst = wT + (size_t)ch*64*K + k0;
  #pragma unroll
  for (int j = 0; j < 2; ++j) {
    const int u = t + j*256;             // 512 8-half units: 64 f x 8 segs
    const int f = u >> 3, seg = u & 7;
    const f16x8 o = *(const f16x8*)&tile[f*72 + seg*8];
    *(f16x8*)(dst + (size_t)f*K + seg*8) = o;
  }
}

// ---------------- Projection via MFMA: C[32 rows][64 f] = A[rows][K] @ wT[f][K]^T ----------------
// Fused: HpT (transposed f16 store) + s/d scores (fast tanh + shuffle reduce).
// grid (N/32, 32 bch), 256 thr. Wave w owns features w*16..+15.
template<int K>
__global__ __launch_bounds__(256) void proj_mfma(
    const _Float16* __restrict__ A,      // [bc][N][K]
    const _Float16* __restrict__ wT,     // [c*HH+h][64][K]
    const float* __restrict__ asrc, const float* __restrict__ adst,
    _Float16* __restrict__ HpT, float* __restrict__ s_out, float* __restrict__ d_out)
{
  __shared__ float sp[4][32], sd[4][32];
  const int bch = blockIdx.y;
  const int h = bch % HH; const int bc = bch / HH; const int c = bc % CC;
  const int row0 = blockIdx.x*32;
  const int t = threadIdx.x;
  const int w = t >> 6, lane = t & 63;
  const int colr = lane & 15, quad = lane >> 4;

  const _Float16* Arow0 = A + ((size_t)bc*NN + row0 + colr)*K;
  const _Float16* Arow1 = Arow0 + (size_t)16*K;
  const _Float16* Brow  = wT + ((size_t)(c*HH + h)*64 + w*16 + colr)*K;

  f32x4 acc0 = {0.f,0.f,0.f,0.f}, acc1 = {0.f,0.f,0.f,0.f};
  #pragma unroll 4
  for (int kb = 0; kb < K; kb += 32) {
    const f16x8 a0 = *(const f16x8*)(Arow0 + kb + quad*8);
    const f16x8 a1 = *(const f16x8*)(Arow1 + kb + quad*8);
    const f16x8 bf = *(const f16x8*)(Brow  + kb + quad*8);
    acc0 = __builtin_amdgcn_mfma_f32_16x16x32_f16(a0, bf, acc0, 0, 0, 0);
    acc1 = __builtin_amdgcn_mfma_f32_16x16x32_f16(a1, bf, acc1, 0, 0, 0);
  }

  const float af = asrc[(c*HH + h)*64 + w*16 + colr];
  const float bf_ = adst[(c*HH + h)*64 + w*16 + colr];
  _Float16* HT = HpT + ((size_t)bch*64 + w*16 + colr)*NN + row0;

  #pragma unroll
  for (int mt = 0; mt < 2; ++mt) {
    const f32x4 a = mt ? acc1 : acc0;
    f16x4 hv;
    #pragma unroll
    for (int i = 0; i < 4; ++i) {
      const float v = a[i];
      hv[i] = (_Float16)v;
      const float ex = __expf(2.f*v);
      const float th = 1.f - 2.f/(ex + 1.f);         // tanh(v), overflow-safe
      float ps = th * af, pd = th * bf_;
      #pragma unroll
      for (int off = 1; off < 16; off <<= 1) {
        ps += __shfl_xor(ps, off);
        pd += __shfl_xor(pd, off);
      }
      if (colr == 0) {
        sp[w][mt*16 + quad*4 + i] = ps;
        sd[w][mt*16 + quad*4 + i] = pd;
      }
    }
    *(f16x4*)(HT + mt*16 + quad*4) = hv;
  }
  __syncthreads();
  if (t < 32) {
    const float sv = sp[0][t] + sp[1][t] + sp[2][t] + sp[3][t];
    const float dv = sd[0][t] + sd[1][t] + sd[2][t] + sd[3][t];
    s_out[bch*NN + row0 + t] = sv;
    d_out[bch*NN + row0 + t] = dv;
  }
}

// ---------------- Fused attention: P on-the-fly -> MFMA PV -> normalize ----------------
template<int LAYER>
__global__ __launch_bounds__(256) void attn_mfma(
    const _Float16* __restrict__ HpT, const float* __restrict__ s_arr,
    const float* __restrict__ d_arr, const unsigned long long* __restrict__ bmg,
    _Float16* __restrict__ outp)
{
  __shared__ __align__(16) _Float16 Bl[64*136];   // HpT chunk [f][136 (128 k + pad)]
  __shared__ __align__(16) _Float16 Al[32*136];   // P chunk  [r][136]
  __shared__ __align__(16) float d_lds[NN];
  __shared__ float dsum_lds[32];
  __shared__ float red4[4];
  const int bch = blockIdx.y;
  const int b = bch / (CC*HH);
  const int row0 = blockIdx.x*32;
  const int t = threadIdx.x;
  const int w = t >> 6, lane = t & 63;

  float4 dv4 = ((const float4*)(d_arr + (size_t)bch*NN))[t];
  ((float4*)d_lds)[t] = dv4;
  float mx = fmaxf(fmaxf(dv4.x, dv4.y), fmaxf(dv4.z, dv4.w));
  #pragma unroll
  for (int off = 1; off < 64; off <<= 1) mx = fmaxf(mx, __shfl_xor(mx, off));
  if (lane == 0) red4[w] = mx;
  __syncthreads();
  const float maxd = fmaxf(fmaxf(red4[0], red4[1]), fmaxf(red4[2], red4[3]));

  const int pr = t >> 3, pk = t & 7;
  const int rowg = row0 + pr;
  const float s_raw = s_arr[(size_t)bch*NN + rowg];
  const float so = s_raw + maxd;
  const float offs = fmaxf(so, 0.2f*so);          // lrelu(s+maxd) >= lrelu(s+d)
  const unsigned long long* bmrow = bmg + ((size_t)b*NN + rowg)*16;
  float dsum = 0.f;
  f32x4 acc0 = {0.f,0.f,0.f,0.f}, acc1 = {0.f,0.f,0.f,0.f};
  const _Float16* Bg = HpT + (size_t)bch*64*NN;
  const int colr = lane & 15, quad = lane >> 4;

  for (int kc = 0; kc < NN; kc += 128) {
    #pragma unroll
    for (int j = 0; j < 4; ++j) {
      const int u = t + j*256;
      const int f = u >> 4, seg = u & 15;
      *(uint4*)&Bl[f*136 + seg*8] = *(const uint4*)(Bg + (size_t)f*NN + kc + seg*8);
    }
    const int kg0 = kc + pk*16;
    const unsigned mb = (unsigned)((bmrow[kg0 >> 6] >> (kg0 & 63)) & 0xFFFFull);
    const float4* dp = (const float4*)&d_lds[kg0];
    float4 q0 = dp[0], q1 = dp[1], q2 = dp[2], q3 = dp[3];
    const float dd[16] = {q0.x,q0.y,q0.z,q0.w, q1.x,q1.y,q1.z,q1.w,
                          q2.x,q2.y,q2.z,q2.w, q3.x,q3.y,q3.z,q3.w};
    f16x8 p0, p1;
    #pragma unroll
    for (int i = 0; i < 16; ++i) {
      const float e0 = s_raw + dd[i];
      const float e = fmaxf(e0, 0.2f*e0);
      const float p = ((mb >> i) & 1u) ? __expf(e - offs) : 0.f;
      dsum += p;
      if (i < 8) p0[i] = (_Float16)p; else p1[i-8] = (_Float16)p;
    }
    *(f16x8*)&Al[pr*136 + pk*16]     = p0;
    *(f16x8*)&Al[pr*136 + pk*16 + 8] = p1;
    __syncthreads();
    #pragma unroll
    for (int ks = 0; ks < 4; ++ks) {
      const int kk = ks*32 + quad*8;
      const f16x8 bf = *(const f16x8*)&Bl[(w*16 + colr)*136 + kk];
      const f16x8 a0 = *(const f16x8*)&Al[colr*136 + kk];
      const f16x8 a1 = *(const f16x8*)&Al[(16 + colr)*136 + kk];
      acc0 = __builtin_amdgcn_mfma_f32_16x16x32_f16(a0, bf, acc0, 0, 0, 0);
      acc1 = __builtin_amdgcn_mfma_f32_16x16x32_f16(a1, bf, acc1, 0, 0, 0);
    }
    __syncthreads();
  }
  dsum += __shfl_xor(dsum, 1);
  dsum += __shfl_xor(dsum, 2);
  dsum += __shfl_xor(dsum, 4);
  if (pk == 0) dsum_lds[pr] = dsum;
  __syncthreads();

  const int bc = bch / HH, h = bch % HH;
  #pragma unroll
  for (int mt = 0; mt < 2; ++mt) {
    const f32x4 a = mt ? acc1 : acc0;
    #pragma unroll
    for (int i = 0; i < 4; ++i) {
      const int rr = mt*16 + quad*4 + i;
      const float v = a[i] / dsum_lds[rr];
      if (LAYER == 1) {
        const float o = v > 0.f ? v : expm1f(v);
        outp[((size_t)bc*NN + row0 + rr)*512 + h*64 + w*16 + colr] = (_Float16)o;
      } else {
        outp[((size_t)bch*NN + row0 + rr)*64 + w*16 + colr] = (_Float16)v;
      }
    }
  }
}

// ---------------- Mean over heads (f16 in) -> fp32 out ----------------
__global__ __launch_bounds__(256) void reduce_heads(
    const _Float16* __restrict__ out2, float* __restrict__ out)
{
  const int o = blockIdx.x*256 + threadIdx.x;
  const int f = o & 63;
  const int n = (o >> 6) & (NN - 1);
  const int bc = o >> 16;
  float acc = 0.f;
  #pragma unroll
  for (int h = 0; h < HH; ++h)
    acc += (float)out2[(((size_t)bc*HH + h)*NN + n)*FFV + f];
  out[o] = acc * 0.125f;
}

extern "C" void kernel_launch(void* const* d_in, const int* in_sizes, int n_in,
                              void* d_out, int out_size, void* d_ws, size_t ws_size,
                              hipStream_t stream)
{
  const float* x   = (const float*)d_in[0];
  const int*   adj = (const int*)d_in[1];
  const float* w1  = (const float*)d_in[2];
  const float* as1 = (const float*)d_in[3];
  const float* ad1 = (const float*)d_in[4];
  const float* w2  = (const float*)d_in[5];
  const float* as2 = (const float*)d_in[6];
  const float* ad2 = (const float*)d_in[7];

  // Workspace (~10.25 MB)
  char* w8 = (char*)d_ws;
  _Float16* HpT = (_Float16*)(w8);                         // 4 MB  [bch][64][N]
  _Float16* XB  = (_Float16*)(w8 + (4u<<20));              // 4 MB  x1 [bc][N][512] then out2 [bch][N][64]
  _Float16* xh  = (_Float16*)(w8 + (8u<<20));              // 512 KB [bc][N][64]
  _Float16* w1T = (_Float16*)(w8 + (8u<<20) + (512u<<10)); // 128 KB [ch][64][64]
  _Float16* w2T = (_Float16*)(w8 + (8u<<20) + (768u<<10)); // 1 MB   [ch][64][512]
  float* s_v = (float*)(w8 + (10u<<20));                   // 128 KB
  float* d_v = (float*)(w8 + (10u<<20) + SVN*4);           // 128 KB
  unsigned long long* bmg = (unsigned long long*)(w8 + (10u<<20) + SVN*8);  // 256 KB

  convert_x<<<256, 256, 0, stream>>>(x, xh);
  transpose_w<<<dim3(1, CC*HH), 256, 0, stream>>>(w1, w1T, 64);
  transpose_w<<<dim3(8, CC*HH), 256, 0, stream>>>(w2, w2T, 512);
  build_mask<<<256, 256, 0, stream>>>(adj, bmg);
  proj_mfma<64><<<dim3(NN/32, BCHN), 256, 0, stream>>>(xh, w1T, as1, ad1, HpT, s_v, d_v);
  attn_mfma<1><<<dim3(NN/32, BCHN), 256, 0, stream>>>(HpT, s_v, d_v, bmg, XB);
  proj_mfma<512><<<dim3(NN/32, BCHN), 256, 0, stream>>>(XB, w2T, as2, ad2, HpT, s_v, d_v);
  attn_mfma<2><<<dim3(NN/32, BCHN), 256, 0, stream>>>(HpT, s_v, d_v, bmg, XB);
  reduce_heads<<<dim3((unsigned)(out_size/256)), 256, 0, stream>>>(XB, (float*)d_out);
}